// Round 11
// baseline (3724.615 us; speedup 1.0000x reference)
//
#include <hip/hip_runtime.h>

typedef unsigned int u32;
typedef unsigned short u16;
typedef unsigned long long u64;
typedef __attribute__((ext_vector_type(2))) _Float16 h2v;
typedef __attribute__((ext_vector_type(4))) _Float16 f16x4;
typedef __attribute__((ext_vector_type(4))) float f32x4;

#define BB 32
#define TT 2048
#define CC 256
#define ESZ 256
#define GG 1024   // 4*es
#define NG 4      // sibling blocks per batch
#define NW 128    // h2 words per batch (256 f16 = 128 pairs)

// ---------------- helpers ----------------
__device__ __forceinline__ float fdot2u(u32 a, u32 b, float c) {
#if __has_builtin(__builtin_amdgcn_fdot2)
  return __builtin_amdgcn_fdot2(__builtin_bit_cast(h2v, a), __builtin_bit_cast(h2v, b), c, false);
#else
  h2v av = __builtin_bit_cast(h2v, a), bv = __builtin_bit_cast(h2v, b);
  return c + (float)av[0] * (float)bv[0] + (float)av[1] * (float)bv[1];
#endif
}

__device__ __forceinline__ float sigm_f(float x) {
  float e = __builtin_amdgcn_exp2f(x * -1.442695041f);
  return __builtin_amdgcn_rcpf(1.0f + e);
}
__device__ __forceinline__ float tanh_f(float x) {
  float e = __builtin_amdgcn_exp2f(x * 2.885390082f);  // exp(2x)
  return 1.0f - 2.0f * __builtin_amdgcn_rcpf(e + 1.0f);
}

// ---------------- kernel 0a: pack W2 (f32 [256][1024] -> h2 rows [128][1024]) ----------------
__global__ void k_pack_w2(const float* __restrict__ W2, u32* __restrict__ W2p) {
  int gid = blockIdx.x * 256 + threadIdx.x;   // m = gid>>10, j = gid&1023
  int m = gid >> 10, j = gid & 1023;
  _Float16 lo = (_Float16)W2[(size_t)(2 * m) * GG + j];
  _Float16 hi = (_Float16)W2[(size_t)(2 * m + 1) * GG + j];
  W2p[gid] = (u32)__builtin_bit_cast(u16, lo) | ((u32)__builtin_bit_cast(u16, hi) << 16);
}

// ---------------- kernel 0b: init exchange slab (slot0 = tag0 + h0; slot1 = 0) ----------------
__global__ void k_init_slab(const float* __restrict__ h0, u64* __restrict__ slab) {
  int idx = blockIdx.x * 256 + threadIdx.x;   // 0..8191
  int slot = idx >> 12;                       // 4096 words per slot
  int rem = idx & 4095;
  int b = rem >> 7, r = rem & 127;
  u64 word = 0;
  if (slot == 0) {
    _Float16 lo = (_Float16)h0[b * ESZ + 2 * r];
    _Float16 hi = (_Float16)h0[b * ESZ + 2 * r + 1];
    u32 h2 = (u32)__builtin_bit_cast(u16, lo) | ((u32)__builtin_bit_cast(u16, hi) << 16);
    word = ((u64)h2 << 32);                   // tag = 0
  }
  slab[(size_t)slot * (BB * NW) + b * NW + r] = word;
}

// ---------------- kernel 1: pre = x@W1 + b1 + b2  (f16 MFMA, out f16 [B*T][1024]) ----------------
__global__ __launch_bounds__(256, 2) void k_pre_gemm(
    const float* __restrict__ x, const float* __restrict__ W1,
    const float* __restrict__ b1, const float* __restrict__ b2,
    _Float16* __restrict__ pre) {
  __shared__ __attribute__((aligned(16))) _Float16 Al[128 * 36];
  __shared__ __attribute__((aligned(16))) _Float16 Bl[64 * 36];
  const int tid = threadIdx.x;
  const int lane = tid & 63, wv = tid >> 6;
  const int wr = wv >> 1, wc = wv & 1;
  const int rowBase = blockIdx.x * 128;
  const int colBase = blockIdx.y * 64;

  f32x4 acc[4][2];
#pragma unroll
  for (int mi = 0; mi < 4; ++mi)
#pragma unroll
    for (int ni = 0; ni < 2; ++ni) acc[mi][ni] = (f32x4){0.f, 0.f, 0.f, 0.f};

  for (int k0 = 0; k0 < 256; k0 += 32) {
#pragma unroll
    for (int i = 0; i < 4; ++i) {
      int fidx = tid + 256 * i;
      int row = fidx >> 3, kc = (fidx & 7) * 4;
      const float4 v = *(const float4*)(x + (size_t)(rowBase + row) * 256 + k0 + kc);
      f16x4 hv = { (_Float16)v.x, (_Float16)v.y, (_Float16)v.z, (_Float16)v.w };
      *(f16x4*)&Al[row * 36 + kc] = hv;
    }
#pragma unroll
    for (int i = 0; i < 8; ++i) {
      int idx = tid + 256 * i;
      int k = idx >> 6, n = idx & 63;
      Bl[n * 36 + k] = (_Float16)W1[(size_t)(k0 + k) * GG + colBase + n];
    }
    __syncthreads();

#pragma unroll
    for (int kk = 0; kk < 2; ++kk) {
      int ka = (lane >> 4) * 4 + kk * 16;
      f16x4 af[4], bf[2];
#pragma unroll
      for (int mi = 0; mi < 4; ++mi)
        af[mi] = *(const f16x4*)&Al[(wr * 64 + mi * 16 + (lane & 15)) * 36 + ka];
#pragma unroll
      for (int ni = 0; ni < 2; ++ni)
        bf[ni] = *(const f16x4*)&Bl[(wc * 32 + ni * 16 + (lane & 15)) * 36 + ka];
#pragma unroll
      for (int mi = 0; mi < 4; ++mi)
#pragma unroll
        for (int ni = 0; ni < 2; ++ni)
          acc[mi][ni] = __builtin_amdgcn_mfma_f32_16x16x16f16(af[mi], bf[ni], acc[mi][ni], 0, 0, 0);
    }
    __syncthreads();
  }

#pragma unroll
  for (int ni = 0; ni < 2; ++ni) {
    int col = colBase + wc * 32 + ni * 16 + (lane & 15);
    float bias = b1[col] + b2[col];
#pragma unroll
    for (int mi = 0; mi < 4; ++mi) {
      int r0 = rowBase + wr * 64 + mi * 16 + (lane >> 4) * 4;
#pragma unroll
      for (int rr = 0; rr < 4; ++rr)
        pre[(size_t)(r0 + rr) * GG + col] = (_Float16)(acc[mi][ni][rr] + bias);
    }
  }
}

// ---------------- kernel 2: the recurrence, 4 CUs per batch ----------------
// Grid 128 = NG*32; bid = g*32 + b. Block g handles es [64g, 64g+64): 256
// threads, 1 gate-column each; wave w = es [64g+16w,+16) x 4 gates; gate
// combine via __shfl. ALL 128 weight h2-rows in arch VGPRs, PINNED ONCE
// (the r5/r8/r9-proven discipline; unpinned r10 got remat'd -> L2-bound).
// h exchange: tagged u64 words {h2pair<<32 | (s+1)}, parity-double-buffered
// LLC slab, agent-scope atomics; readers spin on exactly their 2 words.
__global__ __launch_bounds__(256, 1)
__attribute__((amdgpu_waves_per_eu(1, 1)))
void k_lstm_rec(
    const _Float16* __restrict__ pre, const u32* __restrict__ W2p,
    const float* __restrict__ c0, u64* __restrict__ slab,
    float* __restrict__ out1, float* __restrict__ out2,
    float* __restrict__ hN, float* __restrict__ cN) {
  const int bid = blockIdx.x;
  const int b = bid & 31;        // batch
  const int g = bid >> 5;        // sibling 0..3
  const int t = threadIdx.x;
  const int l = t & 63;          // lane
  const int w = t >> 6;          // wave 0..3
  const int es_l = l & 15;       // es slot within wave
  const int gate = l >> 4;       // 0:f 1:i 2:o 3:ch
  const int E0 = 64 * g + 16 * w;
  const int j = E0 + es_l;               // es index this lane combines
  const int col = j + 256 * gate;        // gate column this lane dots

  // all 128 weight h2-rows for this column in arch VGPRs — pinned ONCE
  u32 wreg[128];
#pragma unroll
  for (int m = 0; m < 128; ++m) wreg[m] = W2p[m * GG + col];
#pragma unroll
  for (int m = 0; m < 128; ++m) asm volatile("" : "+v"(wreg[m]));

  float creg = c0[b * ESZ + j];  // replicated across the 4 gate-lanes of j

  const _Float16* preB = pre + (size_t)b * TT * GG;
  _Float16 q = preB[col];

  const int rA = l;              // this thread's two h2 rows
  const int rB = 64 + l;
  float hv_keep = 0.f;

  for (int s = 0; s < TT; ++s) {
    u64* basep = slab + (size_t)(s & 1) * (BB * NW) + b * NW;
    const u32 want = (u32)s;

    // ---- poll first half (rows 0..63) ----
    u64 wA;
    do {
      wA = __hip_atomic_load(&basep[rA], __ATOMIC_RELAXED, __HIP_MEMORY_SCOPE_AGENT);
    } while ((u32)wA != want);
    u32 hvA = (u32)(wA >> 32);

    float A0 = 0.f, A1 = 0.f;
    float qf = (float)q;
    if (s + 1 < TT) q = preB[(size_t)(s + 1) * GG + col];  // prefetch next pre

    // rows 0..63 (2 chains) — covers writer skew for the second half
#pragma unroll
    for (int m = 0; m < 32; ++m) {
      u32 h0m = (u32)__builtin_amdgcn_readlane((int)hvA, m);
      u32 h1m = (u32)__builtin_amdgcn_readlane((int)hvA, 32 + m);
      A0 = fdot2u(h0m, wreg[m], A0);
      A1 = fdot2u(h1m, wreg[32 + m], A1);
    }

    // ---- poll second half (rows 64..127) ----
    u64 wB;
    do {
      wB = __hip_atomic_load(&basep[rB], __ATOMIC_RELAXED, __HIP_MEMORY_SCOPE_AGENT);
    } while ((u32)wB != want);
    u32 hvB = (u32)(wB >> 32);

    float A2 = 0.f, A3 = 0.f;
#pragma unroll
    for (int m = 0; m < 32; ++m) {
      u32 h2m = (u32)__builtin_amdgcn_readlane((int)hvB, m);
      u32 h3m = (u32)__builtin_amdgcn_readlane((int)hvB, 32 + m);
      A2 = fdot2u(h2m, wreg[64 + m], A2);
      A3 = fdot2u(h3m, wreg[96 + m], A3);
    }

    float v = qf + ((A0 + A1) + (A2 + A3));
    float gv = (gate == 3) ? tanh_f(v) : sigm_f(v);

    // gate combine within wave (no LDS, no barrier)
    float fg = __shfl(gv, es_l);
    float ig = __shfl(gv, es_l + 16);
    float og = __shfl(gv, es_l + 32);
    float ch = __shfl(gv, es_l + 48);
    creg = fg * creg + ig * ch;                 // consistent across the 4 lanes of j
    float hv = og * tanh_f(creg);
    hv_keep = hv;

    // publish FIRST (critical path), outputs after
    float hp = __shfl_xor(hv, 1);               // partner es value
    if (l < 16 && (es_l & 1) == 0) {
      _Float16 lo16 = (_Float16)hv, hi16 = (_Float16)hp;
      u32 h2p = (u32)__builtin_bit_cast(u16, lo16) | ((u32)__builtin_bit_cast(u16, hi16) << 16);
      u64 word = ((u64)h2p << 32) | (u32)(s + 1);
      int r = (E0 + es_l) >> 1;                 // h2 row index
      u64* outp = slab + (size_t)((s + 1) & 1) * (BB * NW) + b * NW + r;
      __hip_atomic_store(outp, word, __ATOMIC_RELAXED, __HIP_MEMORY_SCOPE_AGENT);
    }

    if (l < 16) {
      out1[(size_t)b * TT * ESZ + (size_t)s * ESZ + j] = hv;   // [B, T*es]
      out2[(size_t)s * (BB * ESZ) + b * ESZ + j] = hv;         // [T, B, es]
    }
  }

  if (l < 16) {
    hN[b * ESZ + j] = hv_keep;
    cN[b * ESZ + j] = creg;
  }
}

// ---------------- launch ----------------
extern "C" void kernel_launch(void* const* d_in, const int* in_sizes, int n_in,
                              void* d_out, int out_size, void* d_ws, size_t ws_size,
                              hipStream_t stream) {
  const float* x  = (const float*)d_in[0];
  const float* h0 = (const float*)d_in[1];
  const float* c0 = (const float*)d_in[2];
  const float* W1 = (const float*)d_in[3];
  const float* W2 = (const float*)d_in[4];
  const float* b1 = (const float*)d_in[5];
  const float* b2 = (const float*)d_in[6];

  float* out1 = (float*)d_out;
  float* out2 = out1 + (size_t)BB * TT * ESZ;
  float* hN   = out2 + (size_t)BB * TT * ESZ;
  float* cN   = hN + BB * ESZ;

  _Float16* pre = (_Float16*)d_ws;                                  // 128 MB
  u32* W2p = (u32*)((char*)d_ws + (size_t)BB * TT * GG * 2);        // 512 KB
  u64* slab = (u64*)((char*)W2p + 128 * GG * 4);                    // 64 KB

  k_pack_w2<<<512, 256, 0, stream>>>(W2, W2p);
  k_init_slab<<<32, 256, 0, stream>>>(h0, slab);
  k_pre_gemm<<<dim3(512, 16), 256, 0, stream>>>(x, W1, b1, b2, pre);

  k_lstm_rec<<<NG * BB, 256, 0, stream>>>(pre, W2p, c0, slab, out1, out2, hN, cN);
}

// Round 12
// 3266.946 us; speedup vs baseline: 1.1401x; 1.1401x over previous
//
#include <hip/hip_runtime.h>

typedef unsigned int u32;
typedef unsigned short u16;
typedef unsigned long long u64;
typedef __attribute__((ext_vector_type(2))) _Float16 h2v;
typedef __attribute__((ext_vector_type(4))) _Float16 f16x4;
typedef __attribute__((ext_vector_type(4))) float f32x4;

#define BB 32
#define TT 2048
#define CC 256
#define ESZ 256
#define GG 1024   // 4*es
#define NG 8      // sibling blocks per batch (8*32 = 256 blocks = all CUs)
#define NW 128    // h2 words per batch

// ---------------- helpers ----------------
__device__ __forceinline__ float fdot2u(u32 a, u32 b, float c) {
#if __has_builtin(__builtin_amdgcn_fdot2)
  return __builtin_amdgcn_fdot2(__builtin_bit_cast(h2v, a), __builtin_bit_cast(h2v, b), c, false);
#else
  h2v av = __builtin_bit_cast(h2v, a), bv = __builtin_bit_cast(h2v, b);
  return c + (float)av[0] * (float)bv[0] + (float)av[1] * (float)bv[1];
#endif
}

__device__ __forceinline__ float sigm_f(float x) {
  float e = __builtin_amdgcn_exp2f(x * -1.442695041f);
  return __builtin_amdgcn_rcpf(1.0f + e);
}
__device__ __forceinline__ float tanh_f(float x) {
  float e = __builtin_amdgcn_exp2f(x * 2.885390082f);  // exp(2x)
  return 1.0f - 2.0f * __builtin_amdgcn_rcpf(e + 1.0f);
}

// ---------------- kernel 0a: pack W2 (f32 [256][1024] -> h2 rows [128][1024]) ----------------
__global__ void k_pack_w2(const float* __restrict__ W2, u32* __restrict__ W2p) {
  int gid = blockIdx.x * 256 + threadIdx.x;   // m = gid>>10, j = gid&1023
  int m = gid >> 10, j = gid & 1023;
  _Float16 lo = (_Float16)W2[(size_t)(2 * m) * GG + j];
  _Float16 hi = (_Float16)W2[(size_t)(2 * m + 1) * GG + j];
  W2p[gid] = (u32)__builtin_bit_cast(u16, lo) | ((u32)__builtin_bit_cast(u16, hi) << 16);
}

// ---------------- kernel 0b: init exchange slab (slot0 = tag0 + h0; slot1 = 0) ----------------
__global__ void k_init_slab(const float* __restrict__ h0, u64* __restrict__ slab) {
  int idx = blockIdx.x * 256 + threadIdx.x;   // 0..8191
  int slot = idx >> 12;                       // 4096 words per slot
  int rem = idx & 4095;
  int b = rem >> 7, r = rem & 127;
  u64 word = 0;
  if (slot == 0) {
    _Float16 lo = (_Float16)h0[b * ESZ + 2 * r];
    _Float16 hi = (_Float16)h0[b * ESZ + 2 * r + 1];
    u32 h2 = (u32)__builtin_bit_cast(u16, lo) | ((u32)__builtin_bit_cast(u16, hi) << 16);
    word = ((u64)h2 << 32);                   // tag = 0
  }
  slab[(size_t)slot * (BB * NW) + b * NW + r] = word;
}

// ---------------- kernel 1: pre = x@W1 + b1 + b2  (f16 MFMA, out f16 [B*T][1024]) ----------------
__global__ __launch_bounds__(256, 2) void k_pre_gemm(
    const float* __restrict__ x, const float* __restrict__ W1,
    const float* __restrict__ b1, const float* __restrict__ b2,
    _Float16* __restrict__ pre) {
  __shared__ __attribute__((aligned(16))) _Float16 Al[128 * 36];
  __shared__ __attribute__((aligned(16))) _Float16 Bl[64 * 36];
  const int tid = threadIdx.x;
  const int lane = tid & 63, wv = tid >> 6;
  const int wr = wv >> 1, wc = wv & 1;
  const int rowBase = blockIdx.x * 128;
  const int colBase = blockIdx.y * 64;

  f32x4 acc[4][2];
#pragma unroll
  for (int mi = 0; mi < 4; ++mi)
#pragma unroll
    for (int ni = 0; ni < 2; ++ni) acc[mi][ni] = (f32x4){0.f, 0.f, 0.f, 0.f};

  for (int k0 = 0; k0 < 256; k0 += 32) {
#pragma unroll
    for (int i = 0; i < 4; ++i) {
      int fidx = tid + 256 * i;
      int row = fidx >> 3, kc = (fidx & 7) * 4;
      const float4 v = *(const float4*)(x + (size_t)(rowBase + row) * 256 + k0 + kc);
      f16x4 hv = { (_Float16)v.x, (_Float16)v.y, (_Float16)v.z, (_Float16)v.w };
      *(f16x4*)&Al[row * 36 + kc] = hv;
    }
#pragma unroll
    for (int i = 0; i < 8; ++i) {
      int idx = tid + 256 * i;
      int k = idx >> 6, n = idx & 63;
      Bl[n * 36 + k] = (_Float16)W1[(size_t)(k0 + k) * GG + colBase + n];
    }
    __syncthreads();

#pragma unroll
    for (int kk = 0; kk < 2; ++kk) {
      int ka = (lane >> 4) * 4 + kk * 16;
      f16x4 af[4], bf[2];
#pragma unroll
      for (int mi = 0; mi < 4; ++mi)
        af[mi] = *(const f16x4*)&Al[(wr * 64 + mi * 16 + (lane & 15)) * 36 + ka];
#pragma unroll
      for (int ni = 0; ni < 2; ++ni)
        bf[ni] = *(const f16x4*)&Bl[(wc * 32 + ni * 16 + (lane & 15)) * 36 + ka];
#pragma unroll
      for (int mi = 0; mi < 4; ++mi)
#pragma unroll
        for (int ni = 0; ni < 2; ++ni)
          acc[mi][ni] = __builtin_amdgcn_mfma_f32_16x16x16f16(af[mi], bf[ni], acc[mi][ni], 0, 0, 0);
    }
    __syncthreads();
  }

#pragma unroll
  for (int ni = 0; ni < 2; ++ni) {
    int col = colBase + wc * 32 + ni * 16 + (lane & 15);
    float bias = b1[col] + b2[col];
#pragma unroll
    for (int mi = 0; mi < 4; ++mi) {
      int r0 = rowBase + wr * 64 + mi * 16 + (lane >> 4) * 4;
#pragma unroll
      for (int rr = 0; rr < 4; ++rr)
        pre[(size_t)(r0 + rr) * GG + col] = (_Float16)(acc[mi][ni][rr] + bias);
    }
  }
}

// ---------------- kernel 2: the recurrence, 8 CUs per batch ----------------
// Grid 256 = NG*32; bid = g*32 + b. Block g: es [32g, 32g+32). 256 threads:
// wave w -> (set = w>>1, half = w&1); lane l = gate*16 + es_l covers
// es [32g + 16*set, +16) x 4 gates. Each thread dots ONE gate column over
// h2-rows [64*half, 64*half+64): 64 weight VGPRs (<=128-reg safe budget,
// the only residency regime that never spilled in 11 rounds).
// Half-sum via LDS parity buffer + 1 raw s_barrier/step; gate combine via
// __shfl; h exchange via tagged u64 words in a parity-double-buffered LLC
// slab (agent atomics). Block polls ALL 128 words (h0 waves 0..63, h1 waves
// 64..127) -> publish@s+1 after barrier@s transitively follows every
// read@s-1 (wave lockstep + barrier): overwrite-safe.
__global__ __launch_bounds__(256, 1)
__attribute__((amdgpu_waves_per_eu(1, 1)))
void k_lstm_rec(
    const _Float16* __restrict__ pre, const u32* __restrict__ W2p,
    const float* __restrict__ c0, u64* __restrict__ slab,
    float* __restrict__ out1, float* __restrict__ out2,
    float* __restrict__ hN, float* __restrict__ cN) {
  __shared__ float part[2][4][64];   // [parity][wave][lane] h1->h0 partials

  const int bid = blockIdx.x;
  const int b = bid & 31;        // batch
  const int g = bid >> 5;        // sibling 0..7
  const int t = threadIdx.x;
  const int l = t & 63;          // lane
  const int w = t >> 6;          // wave 0..3
  const int half = w & 1;        // k-half (wave-uniform!)
  const int set = w >> 1;        // es sub-block 0..1
  const int es_l = l & 15;
  const int gate = l >> 4;       // 0:f 1:i 2:o 3:ch
  const int E0 = 32 * g + 16 * set;
  const int j = E0 + es_l;               // es index
  const int col = j + 256 * gate;        // gate column

  // 64 weight h2-rows for this column, rows [64*half, 64*half+64)
  u32 wreg[64];
#pragma unroll
  for (int m = 0; m < 64; ++m) wreg[m] = W2p[(64 * half + m) * GG + col];

  float creg = 0.f, hlast = 0.f;
  if (!half) creg = c0[b * ESZ + j];

  const _Float16* preB = pre + (size_t)b * TT * GG;
  _Float16 q = (_Float16)0.f;
  if (!half) q = preB[col];      // only h0 carries pre

  for (int s = 0; s < TT; ++s) {
    // ---- poll own word (1 per lane): word 64*half + l, tag == s ----
    u64* basep = slab + (size_t)(s & 1) * (BB * NW) + b * NW + 64 * half;
    u64 wv_;
    do {
      wv_ = __hip_atomic_load(&basep[l], __ATOMIC_RELAXED, __HIP_MEMORY_SCOPE_AGENT);
    } while ((u32)wv_ != (u32)s);
    u32 hv_ = (u32)(wv_ >> 32);  // h2 row 64*half + l

    // ---- 64-row dot: uniform-src readlane + dot2, 2 chains ----
    float A0 = 0.f, A1 = 0.f;
#pragma unroll
    for (int k = 0; k < 32; ++k) {
      u32 hm0 = (u32)__builtin_amdgcn_readlane((int)hv_, 2 * k);
      u32 hm1 = (u32)__builtin_amdgcn_readlane((int)hv_, 2 * k + 1);
      A0 = fdot2u(hm0, wreg[2 * k], A0);
      A1 = fdot2u(hm1, wreg[2 * k + 1], A1);
    }
    float A = A0 + A1;

    float qf = 0.f;
    if (!half) {
      qf = (float)q;
      if (s + 1 < TT) q = preB[(size_t)(s + 1) * GG + col];  // prefetch
    } else {
      part[s & 1][w][l] = A;     // hand partial to the h0 partner wave
    }

    asm volatile("s_waitcnt lgkmcnt(0)" ::: "memory");
    __builtin_amdgcn_s_barrier();

    if (!half) {                 // wave-uniform branch: h1 waves skip entirely
      float v = A + qf + part[s & 1][w | 1][l];
      float gv = (gate == 3) ? tanh_f(v) : sigm_f(v);

      float fg = __shfl(gv, es_l);
      float ig = __shfl(gv, es_l + 16);
      float og = __shfl(gv, es_l + 32);
      float ch = __shfl(gv, es_l + 48);
      creg = fg * creg + ig * ch;
      float hv = og * tanh_f(creg);
      hlast = hv;

      // publish tagged word (es pair) into the other parity slot
      float hp = __shfl_xor(hv, 1);
      if (l < 16 && (l & 1) == 0) {
        _Float16 lo16 = (_Float16)hv, hi16 = (_Float16)hp;
        u32 h2p = (u32)__builtin_bit_cast(u16, lo16) | ((u32)__builtin_bit_cast(u16, hi16) << 16);
        u64 word = ((u64)h2p << 32) | (u32)(s + 1);
        int r = (E0 + l) >> 1;
        u64* outp = slab + (size_t)((s + 1) & 1) * (BB * NW) + b * NW + r;
        __hip_atomic_store(outp, word, __ATOMIC_RELAXED, __HIP_MEMORY_SCOPE_AGENT);
      }
      if (l < 16) {
        out1[(size_t)b * TT * ESZ + (size_t)s * ESZ + j] = hv;   // [B, T*es]
        out2[(size_t)s * (BB * ESZ) + b * ESZ + j] = hv;         // [T, B, es]
      }
    }
  }

  if (!half && l < 16) {
    hN[b * ESZ + j] = hlast;
    cN[b * ESZ + j] = creg;
  }
}

// ---------------- launch ----------------
extern "C" void kernel_launch(void* const* d_in, const int* in_sizes, int n_in,
                              void* d_out, int out_size, void* d_ws, size_t ws_size,
                              hipStream_t stream) {
  const float* x  = (const float*)d_in[0];
  const float* h0 = (const float*)d_in[1];
  const float* c0 = (const float*)d_in[2];
  const float* W1 = (const float*)d_in[3];
  const float* W2 = (const float*)d_in[4];
  const float* b1 = (const float*)d_in[5];
  const float* b2 = (const float*)d_in[6];

  float* out1 = (float*)d_out;
  float* out2 = out1 + (size_t)BB * TT * ESZ;
  float* hN   = out2 + (size_t)BB * TT * ESZ;
  float* cN   = hN + BB * ESZ;

  _Float16* pre = (_Float16*)d_ws;                                  // 128 MB
  u32* W2p = (u32*)((char*)d_ws + (size_t)BB * TT * GG * 2);        // 512 KB
  u64* slab = (u64*)((char*)W2p + 128 * GG * 4);                    // 64 KB

  k_pack_w2<<<512, 256, 0, stream>>>(W2, W2p);
  k_init_slab<<<32, 256, 0, stream>>>(h0, slab);
  k_pre_gemm<<<dim3(512, 16), 256, 0, stream>>>(x, W1, b1, b2, pre);

  k_lstm_rec<<<NG * BB, 256, 0, stream>>>(pre, W2p, c0, slab, out1, out2, hN, cN);
}

// Round 13
// 3149.966 us; speedup vs baseline: 1.1824x; 1.0371x over previous
//
#include <hip/hip_runtime.h>

typedef unsigned int u32;
typedef unsigned short u16;
typedef unsigned long long u64;
typedef __attribute__((ext_vector_type(2))) _Float16 h2v;
typedef __attribute__((ext_vector_type(4))) _Float16 f16x4;
typedef __attribute__((ext_vector_type(4))) float f32x4;

#define BB 32
#define TT 2048
#define CC 256
#define ESZ 256
#define GG 1024   // 4*es
#define NG 8      // sibling blocks per batch (8*32 = 256 blocks = all CUs)
#define NW 128    // h2 words per batch

// ---------------- helpers ----------------
__device__ __forceinline__ float fdot2u(u32 a, u32 b, float c) {
#if __has_builtin(__builtin_amdgcn_fdot2)
  return __builtin_amdgcn_fdot2(__builtin_bit_cast(h2v, a), __builtin_bit_cast(h2v, b), c, false);
#else
  h2v av = __builtin_bit_cast(h2v, a), bv = __builtin_bit_cast(h2v, b);
  return c + (float)av[0] * (float)bv[0] + (float)av[1] * (float)bv[1];
#endif
}

__device__ __forceinline__ float sigm_f(float x) {
  float e = __builtin_amdgcn_exp2f(x * -1.442695041f);
  return __builtin_amdgcn_rcpf(1.0f + e);
}
__device__ __forceinline__ float tanh_f(float x) {
  float e = __builtin_amdgcn_exp2f(x * 2.885390082f);  // exp(2x)
  return 1.0f - 2.0f * __builtin_amdgcn_rcpf(e + 1.0f);
}

// ---------------- kernel 0a: pack W2 (f32 [256][1024] -> h2 rows [128][1024]) ----------------
__global__ void k_pack_w2(const float* __restrict__ W2, u32* __restrict__ W2p) {
  int gid = blockIdx.x * 256 + threadIdx.x;   // m = gid>>10, j = gid&1023
  int m = gid >> 10, j = gid & 1023;
  _Float16 lo = (_Float16)W2[(size_t)(2 * m) * GG + j];
  _Float16 hi = (_Float16)W2[(size_t)(2 * m + 1) * GG + j];
  W2p[gid] = (u32)__builtin_bit_cast(u16, lo) | ((u32)__builtin_bit_cast(u16, hi) << 16);
}

// ---------------- kernel 0b: init exchange slab (slot0 = tag0 + h0; slot1 = 0) ----------------
__global__ void k_init_slab(const float* __restrict__ h0, u64* __restrict__ slab) {
  int idx = blockIdx.x * 256 + threadIdx.x;   // 0..8191
  int slot = idx >> 12;                       // 4096 words per slot
  int rem = idx & 4095;
  int b = rem >> 7, r = rem & 127;
  u64 word = 0;
  if (slot == 0) {
    _Float16 lo = (_Float16)h0[b * ESZ + 2 * r];
    _Float16 hi = (_Float16)h0[b * ESZ + 2 * r + 1];
    u32 h2 = (u32)__builtin_bit_cast(u16, lo) | ((u32)__builtin_bit_cast(u16, hi) << 16);
    word = ((u64)h2 << 32);                   // tag = 0
  }
  slab[(size_t)slot * (BB * NW) + b * NW + r] = word;
}

// ---------------- kernel 1: pre = x@W1 + b1 + b2  (f16 MFMA, out f16 [B*T][1024]) ----------------
__global__ __launch_bounds__(256, 2) void k_pre_gemm(
    const float* __restrict__ x, const float* __restrict__ W1,
    const float* __restrict__ b1, const float* __restrict__ b2,
    _Float16* __restrict__ pre) {
  __shared__ __attribute__((aligned(16))) _Float16 Al[128 * 36];
  __shared__ __attribute__((aligned(16))) _Float16 Bl[64 * 36];
  const int tid = threadIdx.x;
  const int lane = tid & 63, wv = tid >> 6;
  const int wr = wv >> 1, wc = wv & 1;
  const int rowBase = blockIdx.x * 128;
  const int colBase = blockIdx.y * 64;

  f32x4 acc[4][2];
#pragma unroll
  for (int mi = 0; mi < 4; ++mi)
#pragma unroll
    for (int ni = 0; ni < 2; ++ni) acc[mi][ni] = (f32x4){0.f, 0.f, 0.f, 0.f};

  for (int k0 = 0; k0 < 256; k0 += 32) {
#pragma unroll
    for (int i = 0; i < 4; ++i) {
      int fidx = tid + 256 * i;
      int row = fidx >> 3, kc = (fidx & 7) * 4;
      const float4 v = *(const float4*)(x + (size_t)(rowBase + row) * 256 + k0 + kc);
      f16x4 hv = { (_Float16)v.x, (_Float16)v.y, (_Float16)v.z, (_Float16)v.w };
      *(f16x4*)&Al[row * 36 + kc] = hv;
    }
#pragma unroll
    for (int i = 0; i < 8; ++i) {
      int idx = tid + 256 * i;
      int k = idx >> 6, n = idx & 63;
      Bl[n * 36 + k] = (_Float16)W1[(size_t)(k0 + k) * GG + colBase + n];
    }
    __syncthreads();

#pragma unroll
    for (int kk = 0; kk < 2; ++kk) {
      int ka = (lane >> 4) * 4 + kk * 16;
      f16x4 af[4], bf[2];
#pragma unroll
      for (int mi = 0; mi < 4; ++mi)
        af[mi] = *(const f16x4*)&Al[(wr * 64 + mi * 16 + (lane & 15)) * 36 + ka];
#pragma unroll
      for (int ni = 0; ni < 2; ++ni)
        bf[ni] = *(const f16x4*)&Bl[(wc * 32 + ni * 16 + (lane & 15)) * 36 + ka];
#pragma unroll
      for (int mi = 0; mi < 4; ++mi)
#pragma unroll
        for (int ni = 0; ni < 2; ++ni)
          acc[mi][ni] = __builtin_amdgcn_mfma_f32_16x16x16f16(af[mi], bf[ni], acc[mi][ni], 0, 0, 0);
    }
    __syncthreads();
  }

#pragma unroll
  for (int ni = 0; ni < 2; ++ni) {
    int col = colBase + wc * 32 + ni * 16 + (lane & 15);
    float bias = b1[col] + b2[col];
#pragma unroll
    for (int mi = 0; mi < 4; ++mi) {
      int r0 = rowBase + wr * 64 + mi * 16 + (lane >> 4) * 4;
#pragma unroll
      for (int rr = 0; rr < 4; ++rr)
        pre[(size_t)(r0 + rr) * GG + col] = (_Float16)(acc[mi][ni][rr] + bias);
    }
  }
}

// ---------------- kernel 2: the recurrence, 8 CUs per batch ----------------
// Identical structure to round 12 (fastest so far) with ONE change: the
// 64-entry weight array is PINNED ONCE with empty asm, demand ~89 <= 128 —
// the only residency regime that never failed (r5 law). Without the pin,
// LLVM sinks the invariant loads into the loop (r12: VGPR=48, FETCH +56MB).
__global__ __launch_bounds__(256, 1)
__attribute__((amdgpu_waves_per_eu(1, 1)))
void k_lstm_rec(
    const _Float16* __restrict__ pre, const u32* __restrict__ W2p,
    const float* __restrict__ c0, u64* __restrict__ slab,
    float* __restrict__ out1, float* __restrict__ out2,
    float* __restrict__ hN, float* __restrict__ cN) {
  __shared__ float part[2][4][64];   // [parity][wave][lane] h1->h0 partials

  const int bid = blockIdx.x;
  const int b = bid & 31;        // batch
  const int g = bid >> 5;        // sibling 0..7
  const int t = threadIdx.x;
  const int l = t & 63;          // lane
  const int w = t >> 6;          // wave 0..3
  const int half = w & 1;        // k-half (wave-uniform!)
  const int set = w >> 1;        // es sub-block 0..1
  const int es_l = l & 15;
  const int gate = l >> 4;       // 0:f 1:i 2:o 3:ch
  const int E0 = 32 * g + 16 * set;
  const int j = E0 + es_l;               // es index
  const int col = j + 256 * gate;        // gate column

  // 64 weight h2-rows for this column, rows [64*half, 64*half+64) — pinned ONCE
  u32 wreg[64];
#pragma unroll
  for (int m = 0; m < 64; ++m) wreg[m] = W2p[(64 * half + m) * GG + col];
#pragma unroll
  for (int m = 0; m < 64; ++m) asm volatile("" : "+v"(wreg[m]));

  float creg = 0.f, hlast = 0.f;
  if (!half) creg = c0[b * ESZ + j];

  const _Float16* preB = pre + (size_t)b * TT * GG;
  _Float16 q = (_Float16)0.f;
  if (!half) q = preB[col];      // only h0 carries pre

  for (int s = 0; s < TT; ++s) {
    // ---- poll own word (1 per lane): word 64*half + l, tag == s ----
    u64* basep = slab + (size_t)(s & 1) * (BB * NW) + b * NW + 64 * half;
    u64 wv_;
    do {
      wv_ = __hip_atomic_load(&basep[l], __ATOMIC_RELAXED, __HIP_MEMORY_SCOPE_AGENT);
    } while ((u32)wv_ != (u32)s);
    u32 hv_ = (u32)(wv_ >> 32);  // h2 row 64*half + l

    // ---- 64-row dot: uniform-src readlane + dot2, 2 chains ----
    float A0 = 0.f, A1 = 0.f;
#pragma unroll
    for (int k = 0; k < 32; ++k) {
      u32 hm0 = (u32)__builtin_amdgcn_readlane((int)hv_, 2 * k);
      u32 hm1 = (u32)__builtin_amdgcn_readlane((int)hv_, 2 * k + 1);
      A0 = fdot2u(hm0, wreg[2 * k], A0);
      A1 = fdot2u(hm1, wreg[2 * k + 1], A1);
    }
    float A = A0 + A1;

    float qf = 0.f;
    if (!half) {
      qf = (float)q;
      if (s + 1 < TT) q = preB[(size_t)(s + 1) * GG + col];  // prefetch
    } else {
      part[s & 1][w][l] = A;     // hand partial to the h0 partner wave
    }

    asm volatile("s_waitcnt lgkmcnt(0)" ::: "memory");
    __builtin_amdgcn_s_barrier();

    if (!half) {                 // wave-uniform branch: h1 waves skip entirely
      float v = A + qf + part[s & 1][w | 1][l];
      float gv = (gate == 3) ? tanh_f(v) : sigm_f(v);

      float fg = __shfl(gv, es_l);
      float ig = __shfl(gv, es_l + 16);
      float og = __shfl(gv, es_l + 32);
      float ch = __shfl(gv, es_l + 48);
      creg = fg * creg + ig * ch;
      float hv = og * tanh_f(creg);
      hlast = hv;

      // publish tagged word (es pair) into the other parity slot
      float hp = __shfl_xor(hv, 1);
      if (l < 16 && (l & 1) == 0) {
        _Float16 lo16 = (_Float16)hv, hi16 = (_Float16)hp;
        u32 h2p = (u32)__builtin_bit_cast(u16, lo16) | ((u32)__builtin_bit_cast(u16, hi16) << 16);
        u64 word = ((u64)h2p << 32) | (u32)(s + 1);
        int r = (E0 + l) >> 1;
        u64* outp = slab + (size_t)((s + 1) & 1) * (BB * NW) + b * NW + r;
        __hip_atomic_store(outp, word, __ATOMIC_RELAXED, __HIP_MEMORY_SCOPE_AGENT);
      }
      if (l < 16) {
        out1[(size_t)b * TT * ESZ + (size_t)s * ESZ + j] = hv;   // [B, T*es]
        out2[(size_t)s * (BB * ESZ) + b * ESZ + j] = hv;         // [T, B, es]
      }
    }
  }

  if (!half && l < 16) {
    hN[b * ESZ + j] = hlast;
    cN[b * ESZ + j] = creg;
  }
}

// ---------------- launch ----------------
extern "C" void kernel_launch(void* const* d_in, const int* in_sizes, int n_in,
                              void* d_out, int out_size, void* d_ws, size_t ws_size,
                              hipStream_t stream) {
  const float* x  = (const float*)d_in[0];
  const float* h0 = (const float*)d_in[1];
  const float* c0 = (const float*)d_in[2];
  const float* W1 = (const float*)d_in[3];
  const float* W2 = (const float*)d_in[4];
  const float* b1 = (const float*)d_in[5];
  const float* b2 = (const float*)d_in[6];

  float* out1 = (float*)d_out;
  float* out2 = out1 + (size_t)BB * TT * ESZ;
  float* hN   = out2 + (size_t)BB * TT * ESZ;
  float* cN   = hN + BB * ESZ;

  _Float16* pre = (_Float16*)d_ws;                                  // 128 MB
  u32* W2p = (u32*)((char*)d_ws + (size_t)BB * TT * GG * 2);        // 512 KB
  u64* slab = (u64*)((char*)W2p + 128 * GG * 4);                    // 64 KB

  k_pack_w2<<<512, 256, 0, stream>>>(W2, W2p);
  k_init_slab<<<32, 256, 0, stream>>>(h0, slab);
  k_pre_gemm<<<dim3(512, 16), 256, 0, stream>>>(x, W1, b1, b2, pre);

  k_lstm_rec<<<NG * BB, 256, 0, stream>>>(pre, W2p, c0, slab, out1, out2, hN, cN);
}